// Round 6
// baseline (705.826 us; speedup 1.0000x reference)
//
#include <hip/hip_runtime.h>

// GSSelfAttn: B=2048 windows, N=144 tokens, D=180, H=6 heads, hd=30.
// R6: TWO windows per block (1024 blocks x 576 thr). Occupancy is pinned at
// 1 block/CU (measured R1-R5, independent of LDS/regs), so instead of chasing
// a 2nd block we put 2 independent work streams inside every barrier region:
//  - W stage shared by both windows (window-independent) -> traffic + barriers halved
//  - W(h+1)/Wp prefetched T14-style (loads after mid-barrier, ds_writes between
//    the A and B attention sections) -> stage latency hidden under S/PV-A
//  - per-window code identical to verified R5 (streaming no-max softmax,
//    swapped QK^T, O in registers, swizzled K/Vt/P strips)
// LDS 156672 B: W 36864 | stripsA 41472 | K_A 9216 | Vt_A 9216 | stripsB/K_B/Vt_B.

typedef __bf16 bf16_t;
typedef __bf16 bf16x8 __attribute__((ext_vector_type(8)));
typedef __bf16 bf16x4 __attribute__((ext_vector_type(4)));
typedef float f32x4 __attribute__((ext_vector_type(4)));

#define MFMA16(a, b, c) __builtin_amdgcn_mfma_f32_16x16x32_bf16((a), (b), (c), 0, 0, 0)

static __device__ __forceinline__ f32x4 fzero4() {
    f32x4 z; z[0] = 0.f; z[1] = 0.f; z[2] = 0.f; z[3] = 0.f; return z;
}
static __device__ __forceinline__ bf16x8 bzero8() {
    bf16x8 z;
    #pragma unroll
    for (int i = 0; i < 8; ++i) z[i] = (bf16_t)0.f;
    return z;
}

// ---------------- pack kernel (identical to R5) ----------------
// ws layout (bytes):
//   Wqkv  @ 0      : [h][kt6][nt6][lane64][j8] bf16      = 221184 B
//   Wp    @ 221184 : [half2][kt6][ntl6][lane64][j8] bf16 =  73728 B (half-major)
//   BIASf @ 294912 : [h][wv9][nt9][lane64][r4] bf16      = 248832 B (S^T fragment layout)
//   bqkv  @ 543744 : [h][c96]                 fp32       =   2304 B
__global__ void pack_kernel(const float* __restrict__ wq, const float* __restrict__ bq,
                            const float* __restrict__ wk, const float* __restrict__ bk,
                            const float* __restrict__ wv, const float* __restrict__ bv,
                            const float* __restrict__ wp, const float* __restrict__ bt,
                            bf16_t* __restrict__ Wqkv, bf16_t* __restrict__ Wp,
                            bf16_t* __restrict__ BIASf, float* __restrict__ bqkv)
{
    const int t = blockIdx.x * blockDim.x + threadIdx.x;
    const int stride = gridDim.x * blockDim.x;
    const float scale = 0.18257418583505536f;   // 30^-0.5, folded into Q path

    for (int i = t; i < 6 * 6 * 6 * 512; i += stride) {
        int j = i & 7, lane = (i >> 3) & 63;
        int f = i >> 9;               // [h][kt][nt]
        int nt = f % 6, kt = (f / 6) % 6, h = f / 36;
        int kin = kt * 32 + (lane >> 4) * 8 + j;
        int c = nt * 16 + (lane & 15);       // 0..95
        int sec = c >> 5, d = c & 31;
        float v = 0.f;
        if (kin < 180 && d < 30) {
            int col = h * 30 + d;
            if (sec == 0)      v = wq[kin * 180 + col] * scale;
            else if (sec == 1) v = wk[kin * 180 + col];
            else               v = wv[kin * 180 + col];
        }
        Wqkv[i] = (bf16_t)v;
    }
    for (int i = t; i < 2 * 6 * 6 * 512; i += stride) {
        int j = i & 7, lane = (i >> 3) & 63;
        int f = i >> 9;               // [half][kt][ntl]
        int ntl = f % 6, kt = (f / 6) % 6, half = f / 36;
        int nt = half * 6 + ntl;
        int kin = kt * 32 + (lane >> 4) * 8 + j;
        int hh = kin >> 5, d = kin & 31;
        int cout = nt * 16 + (lane & 15);
        float v = 0.f;
        if (d < 30 && cout < 180) v = wp[(hh * 30 + d) * 180 + cout];
        Wp[i] = (bf16_t)v;
    }
    for (int i = t; i < 6 * 9 * 9 * 64; i += stride) {
        int lane = i & 63;
        int f = i >> 6;               // [h][wv][nt]
        int nt = f % 9, wvq = (f / 9) % 9, h = f / 81;
        int q = wvq * 16 + (lane & 15);
        int qi = q / 12, qj = q % 12;
        #pragma unroll
        for (int r = 0; r < 4; ++r) {
            int k = nt * 16 + (lane >> 4) * 4 + r;
            int ki = k / 12, kj = k % 12;
            int rel = (qi - ki + 11) * 23 + (qj - kj + 11);
            BIASf[i * 4 + r] = (bf16_t)bt[rel * 6 + h];
        }
    }
    for (int i = t; i < 576; i += stride) {
        int c = i % 96, h = i / 96;
        int sec = c >> 5, d = c & 31;
        float v = 0.f;
        if (d < 30) {
            if (sec == 0)      v = bq[h * 30 + d] * scale;
            else if (sec == 1) v = bk[h * 30 + d];
            else               v = bv[h * 30 + d];
        }
        bqkv[i] = v;
    }
}

// ---------------- fused attention kernel, 2 windows per block ----------------
__global__ __launch_bounds__(576, 3)
void attn_kernel(const float* __restrict__ gs,
                 const bf16_t* __restrict__ Wqkv, const bf16_t* __restrict__ Wp,
                 const bf16_t* __restrict__ BIASf, const float* __restrict__ bqkv,
                 const float* __restrict__ bp, float* __restrict__ out)
{
    __shared__ __align__(16) unsigned char smem[156672];

    const int tid = threadIdx.x;
    const int lane = tid & 63;
    const int wv = tid >> 6;          // wave id = M-strip 0..8
    const int l15 = lane & 15;
    const int lg = lane >> 4;         // 0..3

    constexpr int W_BASE = 0;
    constexpr int ST_[2] = {36864, 96768};
    constexpr int K_[2]  = {78336, 138240};
    constexpr int VT_[2] = {87552, 147456};

    const int winA = blockIdx.x * 2;

    // ---- prefetch W(0) (completes during gs loads) ----
    int4 wld[4];
    #pragma unroll
    for (int i = 0; i < 4; ++i)
        wld[i] = *(const int4*)((const char*)Wqkv + (tid + i * 576) * 16);

    // ---- gs A-fragments for both windows ----
    bf16x8 xa[2][6];
    #pragma unroll
    for (int w = 0; w < 2; ++w) {
        const float* __restrict__ gw = gs + (size_t)(winA + w) * 25920;
        const int row = wv * 16 + l15;
        const float4* __restrict__ g4 = (const float4*)(gw + row * 180);
        #pragma unroll
        for (int kt = 0; kt < 6; ++kt) {
            const int c0 = kt * 32 + lg * 8;
            float4 lo = {0.f, 0.f, 0.f, 0.f}, hi = {0.f, 0.f, 0.f, 0.f};
            if (c0 + 4 <= 180) lo = g4[c0 >> 2];
            if (c0 + 8 <= 180) hi = g4[(c0 >> 2) + 1];
            bf16x8 v;
            v[0] = (bf16_t)lo.x; v[1] = (bf16_t)lo.y; v[2] = (bf16_t)lo.z; v[3] = (bf16_t)lo.w;
            v[4] = (bf16_t)hi.x; v[5] = (bf16_t)hi.y; v[6] = (bf16_t)hi.z; v[7] = (bf16_t)hi.w;
            xa[w][kt] = v;
        }
    }
    // ---- stage W(0) ----
    #pragma unroll
    for (int i = 0; i < 4; ++i)
        *(int4*)(smem + W_BASE + (tid + i * 576) * 16) = wld[i];
    __syncthreads();

    bf16x8 ao[2][6];                  // per-head O A-fragments (persistent)
    const int pswz = (l15 & 6) << 3;

    #pragma unroll
    for (int h = 0; h < 6; ++h) {
        // ---- QKV GEMM + scatter, both windows (W shared) ----
        bf16_t q8[2][8];
        // hoisted per-head qkv bias (same for both windows)
        float bq6[6];
        #pragma unroll
        for (int nt = 0; nt < 6; ++nt) bq6[nt] = bqkv[h * 96 + nt * 16 + l15];

        #pragma unroll
        for (int w = 0; w < 2; ++w) {
            f32x4 acc[6];
            #pragma unroll
            for (int nt = 0; nt < 6; ++nt) acc[nt] = fzero4();
            __builtin_amdgcn_s_setprio(1);
            #pragma unroll
            for (int kt = 0; kt < 6; ++kt) {
                #pragma unroll
                for (int nt = 0; nt < 6; ++nt) {
                    bf16x8 bw = *(const bf16x8*)(smem + W_BASE + ((kt * 6 + nt) * 64 + lane) * 16);
                    acc[nt] = MFMA16(xa[w][kt], bw, acc[nt]);
                }
            }
            __builtin_amdgcn_s_setprio(0);

            const int row0 = wv * 16 + lg * 4;
            #pragma unroll
            for (int nt = 0; nt < 6; ++nt) {
                const float bias = bq6[nt];
                const int sec = nt >> 1;
                const int d32 = ((nt & 1) << 4) + l15;
                const int vswz = (wv < 8) ? (((d32 >> 2) & 3) << 4) : 0;
                #pragma unroll
                for (int r = 0; r < 4; ++r) {
                    const int rr = row0 + r;
                    const bf16_t bvl = (bf16_t)(acc[nt][r] + bias);
                    if (sec == 0)
                        q8[w][(nt & 1) * 4 + r] = bvl;
                    else if (sec == 1)
                        *(bf16_t*)(smem + K_[w] + rr * 64 + ((d32 * 2) ^ ((rr & 6) << 3))) = bvl;
                    else
                        *(bf16_t*)(smem + VT_[w] + d32 * 288 + ((rr * 2) ^ vswz)) = bvl;
                }
            }
        }
        __syncthreads();              // K/Vt visible; W(h) reads done

        // ---- prefetch next stage (W(h+1), or Wp half0 at h=5) ----
        int4 wn[4];
        {
            const char* __restrict__ nsrc =
                (h < 5) ? ((const char*)Wqkv + (h + 1) * 36864) : (const char*)Wp;
            #pragma unroll
            for (int i = 0; i < 4; ++i)
                wn[i] = *(const int4*)(nsrc + (tid + i * 576) * 16);
        }

        // ---- S/softmax/P/PV/O for window A, then stage-write W, then window B ----
        #pragma unroll
        for (int w = 0; w < 2; ++w) {
            char* const pb = (char*)smem + ST_[w] + wv * 4608;

            // Q transpose through own strip chunk0 -> B-fragment aq
            #pragma unroll
            for (int r = 0; r < 4; ++r) {
                const int row = lg * 4 + r;
                const int swz = (row & 6) << 3;
                *(bf16_t*)(pb + row * 64 + ((l15 * 2) ^ swz))      = q8[w][r];
                *(bf16_t*)(pb + row * 64 + ((l15 * 2 + 32) ^ swz)) = q8[w][4 + r];
            }
            asm volatile("" ::: "memory");
            bf16x8 aq = *(const bf16x8*)(pb + l15 * 64 + ((lg * 16) ^ ((l15 & 6) << 3)));
            asm volatile("" ::: "memory");

            // streaming S^T -> exp -> P (no max subtraction; S ~ N(0,1))
            float sum = 0.f;
            #pragma unroll
            for (int nt = 0; nt < 9; ++nt) {
                const int krow = nt * 16 + l15;
                bf16x8 kf = *(const bf16x8*)(smem + K_[w] + krow * 64 +
                                             ((lg * 16) ^ ((krow & 6) << 3)));
                f32x4 sv = MFMA16(kf, aq, fzero4());
                bf16x4 b4 = *(const bf16x4*)(BIASf +
                            (size_t)((((h * 9 + wv) * 9 + nt) * 64 + lane) * 4));
                bf16x4 pw;
                #pragma unroll
                for (int r = 0; r < 4; ++r) {
                    float p = exp2f((sv[r] + (float)b4[r]) * 1.4426950408889634f);
                    sum += p;
                    pw[r] = (bf16_t)p;
                }
                if (nt < 8)
                    *(bf16x4*)(pb + (nt >> 1) * 1024 + l15 * 64 +
                               ((((nt & 1) << 5) + lg * 8) ^ pswz)) = pw;
                else
                    *(bf16x4*)(pb + 4096 + l15 * 32 + lg * 8) = pw;
            }
            sum += __shfl_xor(sum, 16, 64);
            sum += __shfl_xor(sum, 32, 64);
            const float rinv = 1.f / sum;
            asm volatile("" ::: "memory");

            // PV: O(strip)[16x32] = P[16x144] @ Vt^T (tail predicated)
            f32x4 o0 = fzero4(), o1 = fzero4();
            __builtin_amdgcn_s_setprio(1);
            #pragma unroll
            for (int kt = 0; kt < 4; ++kt) {
                const int vs0 = ((l15 >> 2) & 3) << 4;
                bf16x8 ap  = *(const bf16x8*)(pb + kt * 1024 + l15 * 64 + ((lg * 16) ^ pswz));
                bf16x8 bv0 = *(const bf16x8*)(smem + VT_[w] + l15 * 288 + kt * 64 + ((lg * 16) ^ vs0));
                bf16x8 bv1 = *(const bf16x8*)(smem + VT_[w] + (16 + l15) * 288 + kt * 64 + ((lg * 16) ^ vs0));
                o0 = MFMA16(ap, bv0, o0);
                o1 = MFMA16(ap, bv1, o1);
            }
            {   // tail: tokens 128..143 (lg 0,1 read; lg 2,3 contribute zeros)
                bf16x8 ap  = bzero8();
                bf16x8 bv0 = bzero8();
                bf16x8 bv1 = bzero8();
                if (lg < 2) {
                    ap  = *(const bf16x8*)(pb + 4096 + l15 * 32 + lg * 16);
                    bv0 = *(const bf16x8*)(smem + VT_[w] + l15 * 288 + 256 + lg * 16);
                    bv1 = *(const bf16x8*)(smem + VT_[w] + (16 + l15) * 288 + 256 + lg * 16);
                }
                o0 = MFMA16(ap, bv0, o0);
                o1 = MFMA16(ap, bv1, o1);
            }
            __builtin_amdgcn_s_setprio(0);

            // normalize + transpose 16x32 O slice through chunk0 -> ao[w][h]
            asm volatile("" ::: "memory");
            #pragma unroll
            for (int r = 0; r < 4; ++r) {
                const float rq = __shfl(rinv, lg * 4 + r, 16);
                const int row = lg * 4 + r;
                const int swz = (row & 6) << 3;
                *(bf16_t*)(pb + row * 64 + ((l15 * 2) ^ swz))      = (bf16_t)(o0[r] * rq);
                *(bf16_t*)(pb + row * 64 + ((l15 * 2 + 32) ^ swz)) = (bf16_t)(o1[r] * rq);
            }
            asm volatile("" ::: "memory");
            ao[w][h] = *(const bf16x8*)(pb + l15 * 64 + ((lg * 16) ^ ((l15 & 6) << 3)));

            // stage-write next W between the A and B sections (hidden latency)
            if (w == 0) {
                #pragma unroll
                for (int i = 0; i < 4; ++i)
                    *(int4*)(smem + W_BASE + (tid + i * 576) * 16) = wn[i];
            }
        }
        __syncthreads();              // next-W visible; strips/K/Vt reads done
    }

    // ---- output projection; W region holds Wp half0; prefetch half1 -> ST_A ----
    int4 wp1[4];
    #pragma unroll
    for (int i = 0; i < 4; ++i)
        wp1[i] = *(const int4*)((const char*)Wp + 36864 + (tid + i * 576) * 16);

    #pragma unroll
    for (int w = 0; w < 2; ++w) {
        float* __restrict__ og = out + (size_t)(winA + w) * 25920;
        f32x4 accp[6];
        #pragma unroll
        for (int nt = 0; nt < 6; ++nt) accp[nt] = fzero4();
        __builtin_amdgcn_s_setprio(1);
        #pragma unroll
        for (int kt = 0; kt < 6; ++kt) {
            #pragma unroll
            for (int nt = 0; nt < 6; ++nt) {
                bf16x8 bw = *(const bf16x8*)(smem + W_BASE + ((kt * 6 + nt) * 64 + lane) * 16);
                accp[nt] = MFMA16(ao[w][kt], bw, accp[nt]);
            }
        }
        __builtin_amdgcn_s_setprio(0);
        #pragma unroll
        for (int nt = 0; nt < 6; ++nt) {
            const int col = nt * 16 + l15;        // < 96, always valid
            const float bias = bp[col];
            #pragma unroll
            for (int r = 0; r < 4; ++r) {
                const int row = wv * 16 + lg * 4 + r;
                og[row * 180 + col] = accp[nt][r] + bias;
            }
        }
        if (w == 0) {                 // stage Wp half1 into dead strip region A
            #pragma unroll
            for (int i = 0; i < 4; ++i)
                *(int4*)(smem + ST_[0] + (tid + i * 576) * 16) = wp1[i];
        }
    }
    __syncthreads();                  // half1 staged

    #pragma unroll
    for (int w = 0; w < 2; ++w) {
        float* __restrict__ og = out + (size_t)(winA + w) * 25920;
        f32x4 accp[6];
        #pragma unroll
        for (int nt = 0; nt < 6; ++nt) accp[nt] = fzero4();
        __builtin_amdgcn_s_setprio(1);
        #pragma unroll
        for (int kt = 0; kt < 6; ++kt) {
            #pragma unroll
            for (int nt = 0; nt < 6; ++nt) {
                bf16x8 bw = *(const bf16x8*)(smem + ST_[0] + ((kt * 6 + nt) * 64 + lane) * 16);
                accp[nt] = MFMA16(ao[w][kt], bw, accp[nt]);
            }
        }
        __builtin_amdgcn_s_setprio(0);
        #pragma unroll
        for (int nt = 0; nt < 6; ++nt) {
            const int col = 96 + nt * 16 + l15;
            if (col < 180) {
                const float bias = bp[col];
                #pragma unroll
                for (int r = 0; r < 4; ++r) {
                    const int row = wv * 16 + lg * 4 + r;
                    og[row * 180 + col] = accp[nt][r] + bias;
                }
            }
        }
    }
}

extern "C" void kernel_launch(void* const* d_in, const int* in_sizes, int n_in,
                              void* d_out, int out_size, void* d_ws, size_t ws_size,
                              hipStream_t stream) {
    const float* gs = (const float*)d_in[0];
    const float* wq = (const float*)d_in[1];
    const float* bq = (const float*)d_in[2];
    const float* wk = (const float*)d_in[3];
    const float* bk = (const float*)d_in[4];
    const float* wv = (const float*)d_in[5];
    const float* bv = (const float*)d_in[6];
    const float* wp = (const float*)d_in[7];
    const float* bp = (const float*)d_in[8];
    const float* bt = (const float*)d_in[9];

    char* ws = (char*)d_ws;
    bf16_t* Wqkv  = (bf16_t*)(ws);
    bf16_t* Wp    = (bf16_t*)(ws + 221184);
    bf16_t* BIASf = (bf16_t*)(ws + 294912);
    float*  bqkv  = (float*)(ws + 543744);

    pack_kernel<<<256, 256, 0, stream>>>(wq, bq, wk, bk, wv, bv, wp, bt,
                                         Wqkv, Wp, BIASf, bqkv);
    attn_kernel<<<1024, 576, 0, stream>>>(gs, Wqkv, Wp, BIASf, bqkv, bp, (float*)d_out);
}

// Round 7
// 344.255 us; speedup vs baseline: 2.0503x; 2.0503x over previous
//
#include <hip/hip_runtime.h>

// GSSelfAttn: B=2048 windows, N=144 tokens, D=180, H=6 heads, hd=30.
// R7: single-window (R5 base), spill-free (__launch_bounds__(576,2)),
// W-stage double-buffered + prefetched off the critical path (2 barriers/head),
// log2e folded into Wq/bq/BIASf (softmax inner = add+exp2).
// LDS 133632 B: WB0 36864 | WB1 36864 | strips 41472 | K 9216 | Vt 9216.

typedef __bf16 bf16_t;
typedef __bf16 bf16x8 __attribute__((ext_vector_type(8)));
typedef __bf16 bf16x4 __attribute__((ext_vector_type(4)));
typedef float f32x4 __attribute__((ext_vector_type(4)));

#define MFMA16(a, b, c) __builtin_amdgcn_mfma_f32_16x16x32_bf16((a), (b), (c), 0, 0, 0)

static __device__ __forceinline__ f32x4 fzero4() {
    f32x4 z; z[0] = 0.f; z[1] = 0.f; z[2] = 0.f; z[3] = 0.f; return z;
}
static __device__ __forceinline__ bf16x8 bzero8() {
    bf16x8 z;
    #pragma unroll
    for (int i = 0; i < 8; ++i) z[i] = (bf16_t)0.f;
    return z;
}

// ---------------- pack kernel ----------------
// ws layout (bytes):
//   Wqkv  @ 0      : [h][kt6][nt6][lane64][j8] bf16      = 221184 B  (Q cols pre-scaled by 30^-.5*log2e)
//   Wp    @ 221184 : [half2][kt6][ntl6][lane64][j8] bf16 =  73728 B  (half-major)
//   BIASf @ 294912 : [h][wv9][nt9][lane64][r4] bf16      = 248832 B  (S^T fragment layout, *log2e)
//   bqkv  @ 543744 : [h][c96]                 fp32       =   2304 B  (Q part *scale*log2e)
__global__ void pack_kernel(const float* __restrict__ wq, const float* __restrict__ bq,
                            const float* __restrict__ wk, const float* __restrict__ bk,
                            const float* __restrict__ wv, const float* __restrict__ bv,
                            const float* __restrict__ wp, const float* __restrict__ bt,
                            bf16_t* __restrict__ Wqkv, bf16_t* __restrict__ Wp,
                            bf16_t* __restrict__ BIASf, float* __restrict__ bqkv)
{
    const int t = blockIdx.x * blockDim.x + threadIdx.x;
    const int stride = gridDim.x * blockDim.x;
    const float L2E = 1.4426950408889634f;
    const float qscale = 0.18257418583505536f * L2E;   // 30^-0.5 * log2e, folded into Q

    for (int i = t; i < 6 * 6 * 6 * 512; i += stride) {
        int j = i & 7, lane = (i >> 3) & 63;
        int f = i >> 9;               // [h][kt][nt]
        int nt = f % 6, kt = (f / 6) % 6, h = f / 36;
        int kin = kt * 32 + (lane >> 4) * 8 + j;
        int c = nt * 16 + (lane & 15);       // 0..95
        int sec = c >> 5, d = c & 31;
        float v = 0.f;
        if (kin < 180 && d < 30) {
            int col = h * 30 + d;
            if (sec == 0)      v = wq[kin * 180 + col] * qscale;
            else if (sec == 1) v = wk[kin * 180 + col];
            else               v = wv[kin * 180 + col];
        }
        Wqkv[i] = (bf16_t)v;
    }
    for (int i = t; i < 2 * 6 * 6 * 512; i += stride) {
        int j = i & 7, lane = (i >> 3) & 63;
        int f = i >> 9;               // [half][kt][ntl]
        int ntl = f % 6, kt = (f / 6) % 6, half = f / 36;
        int nt = half * 6 + ntl;
        int kin = kt * 32 + (lane >> 4) * 8 + j;
        int hh = kin >> 5, d = kin & 31;
        int cout = nt * 16 + (lane & 15);
        float v = 0.f;
        if (d < 30 && cout < 180) v = wp[(hh * 30 + d) * 180 + cout];
        Wp[i] = (bf16_t)v;
    }
    // relative-position bias (pre-multiplied by log2e) in S^T-fragment layout:
    // BIASf[(((h*9+wv)*9+nt)*64+lane)*4+r] = L2E*bias[h][q=wv*16+(lane&15)][k=nt*16+(lane>>4)*4+r]
    for (int i = t; i < 6 * 9 * 9 * 64; i += stride) {
        int lane = i & 63;
        int f = i >> 6;               // [h][wv][nt]
        int nt = f % 9, wvq = (f / 9) % 9, h = f / 81;
        int q = wvq * 16 + (lane & 15);
        int qi = q / 12, qj = q % 12;
        #pragma unroll
        for (int r = 0; r < 4; ++r) {
            int k = nt * 16 + (lane >> 4) * 4 + r;
            int ki = k / 12, kj = k % 12;
            int rel = (qi - ki + 11) * 23 + (qj - kj + 11);
            BIASf[i * 4 + r] = (bf16_t)(bt[rel * 6 + h] * L2E);
        }
    }
    for (int i = t; i < 576; i += stride) {
        int c = i % 96, h = i / 96;
        int sec = c >> 5, d = c & 31;
        float v = 0.f;
        if (d < 30) {
            if (sec == 0)      v = bq[h * 30 + d] * qscale;
            else if (sec == 1) v = bk[h * 30 + d];
            else               v = bv[h * 30 + d];
        }
        bqkv[i] = v;
    }
}

// ---------------- fused attention kernel ----------------
// block = 576 threads = 9 waves; wave w owns M-strip rows [16w, 16w+16)
// LDS map (133632 B):
//   WB[0] @ 0      : 36864 B   (QKV head weights, double-buffered; Wp halves reuse)
//   WB[1] @ 36864  : 36864 B
//   strips@ 73728  : 9 x 4608 B (P chunks kt0..3 [16q][32tok] swizzled + tail 512B;
//                    Q/O transposes reuse chunk0 at distinct times)
//   K     @ 115200 : [144][32] bf16 stride 64, swizzle byte^=((row&6)<<3)
//   Vt    @ 124416 : [32 d][144 tok] bf16 stride 288; 64B-blocks 0..3 swizzled
// Pipeline per head h (2 barriers): QKV GEMM reads WB[h&1] (staged last head);
// scatter K/Vt; BAR-A; issue W(h+1) global loads; attn (S->exp->P->PV->O);
// ds_write W(h+1) -> WB[(h+1)&1]; BAR-B.
__global__ __launch_bounds__(576, 2)
void attn_kernel(const float* __restrict__ gs,
                 const bf16_t* __restrict__ Wqkv, const bf16_t* __restrict__ Wp,
                 const bf16_t* __restrict__ BIASf, const float* __restrict__ bqkv,
                 const float* __restrict__ bp, float* __restrict__ out)
{
    __shared__ __align__(16) unsigned char smem[133632];

    const int tid = threadIdx.x;
    const int lane = tid & 63;
    const int wv = tid >> 6;          // wave id = M-strip 0..8
    const int l15 = lane & 15;
    const int lg = lane >> 4;         // 0..3
    const int win = blockIdx.x;
    const float* __restrict__ gsw = gs + (size_t)win * 25920;

    constexpr int WB0     = 0;
    constexpr int WB1     = 36864;
    constexpr int ST_BASE = 73728;
    constexpr int K_BASE  = 115200;
    constexpr int VT_BASE = 124416;

    // ---- prefetch W(0) (arrives during gs loads) ----
    int4 wld[4];
    #pragma unroll
    for (int i = 0; i < 4; ++i)
        wld[i] = *(const int4*)((const char*)Wqkv + (tid + i * 576) * 16);

    // ---- gs A-fragments into registers: row = 16*wv + l15, k-tile kt ----
    bf16x8 xa[6];
    {
        const int row = wv * 16 + l15;
        const float4* __restrict__ g4 = (const float4*)(gsw + row * 180);
        #pragma unroll
        for (int kt = 0; kt < 6; ++kt) {
            const int c0 = kt * 32 + lg * 8;
            float4 lo = {0.f, 0.f, 0.f, 0.f}, hi = {0.f, 0.f, 0.f, 0.f};
            if (c0 + 4 <= 180) lo = g4[c0 >> 2];
            if (c0 + 8 <= 180) hi = g4[(c0 >> 2) + 1];
            bf16x8 v;
            v[0] = (bf16_t)lo.x; v[1] = (bf16_t)lo.y; v[2] = (bf16_t)lo.z; v[3] = (bf16_t)lo.w;
            v[4] = (bf16_t)hi.x; v[5] = (bf16_t)hi.y; v[6] = (bf16_t)hi.z; v[7] = (bf16_t)hi.w;
            xa[kt] = v;
        }
    }
    // ---- stage W(0) into WB0 ----
    #pragma unroll
    for (int i = 0; i < 4; ++i)
        *(int4*)(smem + WB0 + (tid + i * 576) * 16) = wld[i];
    __syncthreads();

    bf16x8 ao[6];                     // per-head O A-fragments (persistent)
    char* const pb = (char*)smem + ST_BASE + wv * 4608;   // wave-private strip
    const int pswz = (l15 & 6) << 3;

    #pragma unroll
    for (int h = 0; h < 6; ++h) {
        const int WCUR = (h & 1) ? WB1 : WB0;
        const int WNXT = (h & 1) ? WB0 : WB1;

        // ---- QKV GEMM: acc[nt] = X(strip) @ W[:, nt] ----
        f32x4 acc[6];
        #pragma unroll
        for (int nt = 0; nt < 6; ++nt) acc[nt] = fzero4();
        __builtin_amdgcn_s_setprio(1);
        #pragma unroll
        for (int kt = 0; kt < 6; ++kt) {
            #pragma unroll
            for (int nt = 0; nt < 6; ++nt) {
                bf16x8 bw = *(const bf16x8*)(smem + WCUR + ((kt * 6 + nt) * 64 + lane) * 16);
                acc[nt] = MFMA16(xa[kt], bw, acc[nt]);
            }
        }
        __builtin_amdgcn_s_setprio(0);

        // ---- scatter K,V to LDS; Q stays in registers ----
        bf16_t q8[8];
        {
            const int row0 = wv * 16 + lg * 4;
            #pragma unroll
            for (int nt = 0; nt < 6; ++nt) {
                const float bias = bqkv[h * 96 + nt * 16 + l15];
                const int sec = nt >> 1;
                const int d32 = ((nt & 1) << 4) + l15;
                const int vswz = (wv < 8) ? (((d32 >> 2) & 3) << 4) : 0;
                #pragma unroll
                for (int r = 0; r < 4; ++r) {
                    const int rr = row0 + r;
                    const bf16_t bvl = (bf16_t)(acc[nt][r] + bias);
                    if (sec == 0)
                        q8[(nt & 1) * 4 + r] = bvl;
                    else if (sec == 1)
                        *(bf16_t*)(smem + K_BASE + rr * 64 + ((d32 * 2) ^ ((rr & 6) << 3))) = bvl;
                    else
                        *(bf16_t*)(smem + VT_BASE + d32 * 288 + ((rr * 2) ^ vswz)) = bvl;
                }
            }
        }
        __syncthreads();              // BAR-A: K/Vt visible; WCUR reads done

        // ---- issue next-stage global loads (W(h+1), or Wp half0 at h=5) ----
        int4 wn[4];
        {
            const char* __restrict__ nsrc =
                (h < 5) ? ((const char*)Wqkv + (h + 1) * 36864) : (const char*)Wp;
            #pragma unroll
            for (int i = 0; i < 4; ++i)
                wn[i] = *(const int4*)(nsrc + (tid + i * 576) * 16);
        }

        // ---- Q transpose through own strip chunk0 -> B-fragment aq ----
        #pragma unroll
        for (int r = 0; r < 4; ++r) {
            const int row = lg * 4 + r;
            const int swz = (row & 6) << 3;
            *(bf16_t*)(pb + row * 64 + ((l15 * 2) ^ swz))      = q8[r];
            *(bf16_t*)(pb + row * 64 + ((l15 * 2 + 32) ^ swz)) = q8[4 + r];
        }
        asm volatile("" ::: "memory");
        bf16x8 aq = *(const bf16x8*)(pb + l15 * 64 + ((lg * 16) ^ ((l15 & 6) << 3)));
        asm volatile("" ::: "memory");

        // ---- streaming S^T -> exp2 -> P (no max; S~N(0,1); log2e pre-folded) ----
        float sum = 0.f;
        #pragma unroll
        for (int nt = 0; nt < 9; ++nt) {
            const int krow = nt * 16 + l15;
            bf16x8 kf = *(const bf16x8*)(smem + K_BASE + krow * 64 +
                                         ((lg * 16) ^ ((krow & 6) << 3)));
            f32x4 sv = MFMA16(kf, aq, fzero4());
            bf16x4 b4 = *(const bf16x4*)(BIASf +
                        (size_t)((((h * 9 + wv) * 9 + nt) * 64 + lane) * 4));
            bf16x4 pw;
            #pragma unroll
            for (int r = 0; r < 4; ++r) {
                float p = exp2f(sv[r] + (float)b4[r]);
                sum += p;
                pw[r] = (bf16_t)p;
            }
            if (nt < 8)
                *(bf16x4*)(pb + (nt >> 1) * 1024 + l15 * 64 +
                           ((((nt & 1) << 5) + lg * 8) ^ pswz)) = pw;
            else
                *(bf16x4*)(pb + 4096 + l15 * 32 + lg * 8) = pw;
        }
        sum += __shfl_xor(sum, 16, 64);
        sum += __shfl_xor(sum, 32, 64);
        const float rinv = 1.f / sum;  // normalization deferred to O epilogue
        asm volatile("" ::: "memory");

        // ---- PV: O(strip)[16x32] = P[16x144] @ Vt^T (tail predicated) ----
        f32x4 o0 = fzero4(), o1 = fzero4();
        __builtin_amdgcn_s_setprio(1);
        #pragma unroll
        for (int kt = 0; kt < 4; ++kt) {
            const int vs0 = ((l15 >> 2) & 3) << 4;
            bf16x8 ap  = *(const bf16x8*)(pb + kt * 1024 + l15 * 64 + ((lg * 16) ^ pswz));
            bf16x8 bv0 = *(const bf16x8*)(smem + VT_BASE + l15 * 288 + kt * 64 + ((lg * 16) ^ vs0));
            bf16x8 bv1 = *(const bf16x8*)(smem + VT_BASE + (16 + l15) * 288 + kt * 64 + ((lg * 16) ^ vs0));
            o0 = MFMA16(ap, bv0, o0);
            o1 = MFMA16(ap, bv1, o1);
        }
        {   // tail: tokens 128..143 (lg 0,1 read; lg 2,3 contribute zeros)
            bf16x8 ap  = bzero8();
            bf16x8 bv0 = bzero8();
            bf16x8 bv1 = bzero8();
            if (lg < 2) {
                ap  = *(const bf16x8*)(pb + 4096 + l15 * 32 + lg * 16);
                bv0 = *(const bf16x8*)(smem + VT_BASE + l15 * 288 + 256 + lg * 16);
                bv1 = *(const bf16x8*)(smem + VT_BASE + (16 + l15) * 288 + 256 + lg * 16);
            }
            o0 = MFMA16(ap, bv0, o0);
            o1 = MFMA16(ap, bv1, o1);
        }
        __builtin_amdgcn_s_setprio(0);

        // ---- stage-write next W into WNXT (nobody reads until BAR-B) ----
        #pragma unroll
        for (int i = 0; i < 4; ++i)
            *(int4*)(smem + WNXT + (tid + i * 576) * 16) = wn[i];

        // ---- normalize + transpose 16x32 O slice through chunk0 -> ao[h] ----
        asm volatile("" ::: "memory");
        #pragma unroll
        for (int r = 0; r < 4; ++r) {
            const float rq = __shfl(rinv, lg * 4 + r, 16);
            const int row = lg * 4 + r;
            const int swz = (row & 6) << 3;
            *(bf16_t*)(pb + row * 64 + ((l15 * 2) ^ swz))      = (bf16_t)(o0[r] * rq);
            *(bf16_t*)(pb + row * 64 + ((l15 * 2 + 32) ^ swz)) = (bf16_t)(o1[r] * rq);
        }
        asm volatile("" ::: "memory");
        ao[h] = *(const bf16x8*)(pb + l15 * 64 + ((lg * 16) ^ ((l15 & 6) << 3)));

        __syncthreads();              // BAR-B: WNXT visible; K/Vt/strips reusable
    }

    // ---- output projection: out = O @ Wp + bp; halves pipelined through WB ----
    float* __restrict__ og = out + (size_t)win * 25920;
    // WB0 holds Wp half0 (staged during head 5). Issue half1 loads now.
    int4 wp1[4];
    #pragma unroll
    for (int i = 0; i < 4; ++i)
        wp1[i] = *(const int4*)((const char*)Wp + 36864 + (tid + i * 576) * 16);

    #pragma unroll
    for (int half = 0; half < 2; ++half) {
        const int WH = half ? WB1 : WB0;
        f32x4 accp[6];
        #pragma unroll
        for (int nt = 0; nt < 6; ++nt) accp[nt] = fzero4();
        __builtin_amdgcn_s_setprio(1);
        #pragma unroll
        for (int kt = 0; kt < 6; ++kt) {
            #pragma unroll
            for (int nt = 0; nt < 6; ++nt) {
                bf16x8 bw = *(const bf16x8*)(smem + WH + ((kt * 6 + nt) * 64 + lane) * 16);
                accp[nt] = MFMA16(ao[kt], bw, accp[nt]);
            }
        }
        __builtin_amdgcn_s_setprio(0);
        #pragma unroll
        for (int nt = 0; nt < 6; ++nt) {
            const int col = half * 96 + nt * 16 + l15;
            if (col < 180) {
                const float bias = bp[col];
                #pragma unroll
                for (int r = 0; r < 4; ++r) {
                    const int row = wv * 16 + lg * 4 + r;
                    og[row * 180 + col] = accp[nt][r] + bias;
                }
            }
        }
        if (half == 0) {
            // stage Wp half1 into WB1 (its last reads ended before head-5 BAR-A)
            #pragma unroll
            for (int i = 0; i < 4; ++i)
                *(int4*)(smem + WB1 + (tid + i * 576) * 16) = wp1[i];
            __syncthreads();
        }
    }
}

extern "C" void kernel_launch(void* const* d_in, const int* in_sizes, int n_in,
                              void* d_out, int out_size, void* d_ws, size_t ws_size,
                              hipStream_t stream) {
    const float* gs = (const float*)d_in[0];
    const float* wq = (const float*)d_in[1];
    const float* bq = (const float*)d_in[2];
    const float* wk = (const float*)d_in[3];
    const float* bk = (const float*)d_in[4];
    const float* wv = (const float*)d_in[5];
    const float* bv = (const float*)d_in[6];
    const float* wp = (const float*)d_in[7];
    const float* bp = (const float*)d_in[8];
    const float* bt = (const float*)d_in[9];

    char* ws = (char*)d_ws;
    bf16_t* Wqkv  = (bf16_t*)(ws);
    bf16_t* Wp    = (bf16_t*)(ws + 221184);
    bf16_t* BIASf = (bf16_t*)(ws + 294912);
    float*  bqkv  = (float*)(ws + 543744);

    pack_kernel<<<256, 256, 0, stream>>>(wq, bq, wk, bk, wv, bv, wp, bt,
                                         Wqkv, Wp, BIASf, bqkv);
    attn_kernel<<<2048, 576, 0, stream>>>(gs, Wqkv, Wp, BIASf, bqkv, bp, (float*)d_out);
}